// Round 8
// baseline (55.202 us; speedup 1.0000x reference)
//
#include <hip/hip_runtime.h>
#include <hip/hip_bf16.h>

// BlockLinear: out[h*64+i][b] = sum_j W[h][i][j] * inp[h*64+j][b]
// Round 8: round-7 swapped-operand MFMA structure +
//  (a) non-temporal stores (out never evicts inp from L3),
//  (b) NT=2 / 2048 blocks (backfill over the 4-blocks/CU residency),
//  (c) W loads issued before tile-0 x loads so W-convert waits vmcnt(32)
//      instead of draining.
// Fragment layout (HW-validated r6/r7): lane l holds k = ks*32 + 8*(l>>4)+r;
// C/D: row m = 4*(l>>4)+reg, col n = l&15.

constexpr int H   = 16;
constexpr int D   = 64;
constexpr int B   = 32768;
constexpr int TPB = 128;   // cols per tile per block (4 waves x 32)
constexpr int NT  = 2;     // tiles per block

using bf16x8 = __attribute__((ext_vector_type(8))) short;
using f32x4  = __attribute__((ext_vector_type(4))) float;

__device__ inline unsigned pk2(float a, float b) {
    __hip_bfloat162 h2 = __float22bfloat162_rn(make_float2(a, b));
    union { __hip_bfloat162 h; unsigned u; } c;
    c.h = h2;
    return c.u;   // low 16 = a, high 16 = b
}

__global__ __launch_bounds__(256)
void block_linear_mfma(const float* __restrict__ W,
                       const float* __restrict__ inp,
                       float* __restrict__ out)
{
    const int tid = threadIdx.x;
    const int l   = tid & 63;
    const int wv  = __builtin_amdgcn_readfirstlane(tid >> 6);
    const int h   = blockIdx.y;
    const int l15 = l & 15;
    const int lk8 = (l >> 4) * 8;
    const int lr4 = (l >> 4) * 4;

    // ---- 1) Issue W raw loads first (16 float4; L2-resident).
    float4 wq[4][2][2];
    #pragma unroll
    for (int ni = 0; ni < 4; ++ni) {
        const float* wp = W + ((size_t)h * D + 16 * ni + l15) * D + lk8;
        #pragma unroll
        for (int ks = 0; ks < 2; ++ks) {
            wq[ni][ks][0] = *(const float4*)(wp + ks * 32);
            wq[ni][ks][1] = *(const float4*)(wp + ks * 32 + 4);
        }
    }

    // ---- 2) Issue tile-0 x loads (32 dwords/lane) while W is in flight.
    const size_t blockbase = (size_t)blockIdx.x * (TPB * NT) + wv * 32;
    const float* xb = inp + (size_t)h * D * B + blockbase + l15;

    float xA[2][2][8];
    #pragma unroll
    for (int mi = 0; mi < 2; ++mi)
        #pragma unroll
        for (int ks = 0; ks < 2; ++ks)
            #pragma unroll
            for (int r = 0; r < 8; ++r)
                xA[mi][ks][r] = xb[(size_t)(ks * 32 + lk8 + r) * B + 16 * mi];

    // ---- 3) Convert W (waits only on W's loads: counted vmcnt, x stays in flight).
    bf16x8 bfrag[4][2];
    #pragma unroll
    for (int ni = 0; ni < 4; ++ni)
        #pragma unroll
        for (int ks = 0; ks < 2; ++ks) {
            union { bf16x8 v; unsigned u[4]; } f;
            f.u[0] = pk2(wq[ni][ks][0].x, wq[ni][ks][0].y);
            f.u[1] = pk2(wq[ni][ks][0].z, wq[ni][ks][0].w);
            f.u[2] = pk2(wq[ni][ks][1].x, wq[ni][ks][1].y);
            f.u[3] = pk2(wq[ni][ks][1].z, wq[ni][ks][1].w);
            bfrag[ni][ks] = f.v;
        }

    // ---- 4) Issue tile-1 x loads.
    float xB[2][2][8];
    #pragma unroll
    for (int mi = 0; mi < 2; ++mi)
        #pragma unroll
        for (int ks = 0; ks < 2; ++ks)
            #pragma unroll
            for (int r = 0; r < 8; ++r)
                xB[mi][ks][r] = xb[(size_t)(ks * 32 + lk8 + r) * B + 16 * mi + TPB];

    // ---- 5) Process tiles (convert -> 16 MFMA -> nt float4 stores).
#define PROCESS_TILE(XBUF, T)                                                  \
    do {                                                                       \
        bf16x8 a[2][2];                                                        \
        _Pragma("unroll")                                                      \
        for (int mi = 0; mi < 2; ++mi)                                         \
            _Pragma("unroll")                                                  \
            for (int ks = 0; ks < 2; ++ks) {                                   \
                const float* e = XBUF[mi][ks];                                 \
                union { bf16x8 v; unsigned u[4]; } f;                          \
                f.u[0] = pk2(e[0], e[1]);                                      \
                f.u[1] = pk2(e[2], e[3]);                                      \
                f.u[2] = pk2(e[4], e[5]);                                      \
                f.u[3] = pk2(e[6], e[7]);                                      \
                a[mi][ks] = f.v;                                               \
            }                                                                  \
        const size_t b0 = blockbase + (size_t)(T) * TPB + lr4;                 \
        _Pragma("unroll")                                                      \
        for (int mi = 0; mi < 2; ++mi)                                         \
            _Pragma("unroll")                                                  \
            for (int ni = 0; ni < 4; ++ni) {                                   \
                f32x4 c = {0.f, 0.f, 0.f, 0.f};                                \
                c = __builtin_amdgcn_mfma_f32_16x16x32_bf16(a[mi][0],          \
                        bfrag[ni][0], c, 0, 0, 0);                             \
                c = __builtin_amdgcn_mfma_f32_16x16x32_bf16(a[mi][1],          \
                        bfrag[ni][1], c, 0, 0, 0);                             \
                float* op = out + ((size_t)h * D + 16 * ni + l15) * B          \
                                + b0 + 16 * mi;                                \
                __builtin_nontemporal_store(c, (f32x4*)op);                    \
            }                                                                  \
    } while (0)

    PROCESS_TILE(xA, 0);
    PROCESS_TILE(xB, 1);
#undef PROCESS_TILE
}

extern "C" void kernel_launch(void* const* d_in, const int* in_sizes, int n_in,
                              void* d_out, int out_size, void* d_ws, size_t ws_size,
                              hipStream_t stream) {
    const float* W   = (const float*)d_in[0];
    const float* inp = (const float*)d_in[1];
    float*       out = (float*)d_out;

    dim3 grid(B / (TPB * NT), H);   // 128 x 16 = 2048 workgroups
    block_linear_mfma<<<grid, dim3(256), 0, stream>>>(W, inp, out);
}